// Round 20
// baseline (2369.992 us; speedup 1.0000x reference)
//
#include <hip/hip_runtime.h>
#include <math.h>

#define BB 32
#define TT 50
#define HH 1024
#define DD 512
#define VV 50257
#define G4H 4096

typedef __attribute__((ext_vector_type(8))) short bf16x8;           // 8 bf16 in 4 VGPRs
typedef __attribute__((ext_vector_type(8))) unsigned short u16x8;   // staging vec
typedef __attribute__((ext_vector_type(4))) float f32x4;

__device__ inline unsigned short f2bf(float x) {
    unsigned u = __float_as_uint(x);
    u = (u + 0x7fff + ((u >> 16) & 1)) >> 16;   // RNE
    return (unsigned short)u;
}
__device__ inline float bf2f(unsigned short h) {
    return __uint_as_float(((unsigned)h) << 16);
}
__device__ inline void gl16(const void* g, void* l) {
    __builtin_amdgcn_global_load_lds(
        (const __attribute__((address_space(1))) unsigned int*)g,
        (__attribute__((address_space(3))) unsigned int*)l, 16, 0, 0);
}

// ---------------------------------------------------------------------------
// split fp32 -> (hi, lo) bf16 pair, vectorized x4
// ---------------------------------------------------------------------------
__global__ void split_f32(const float* __restrict__ x,
                          unsigned short* __restrict__ hi,
                          unsigned short* __restrict__ lo, long n4) {
    long i = (long)blockIdx.x * 256 + threadIdx.x;
    long stride = (long)gridDim.x * 256;
    for (; i < n4; i += stride) {
        float4 v = ((const float4*)x)[i];
        ushort4 h, l;
        h.x = f2bf(v.x); l.x = f2bf(v.x - bf2f(h.x));
        h.y = f2bf(v.y); l.y = f2bf(v.y - bf2f(h.y));
        h.z = f2bf(v.z); l.z = f2bf(v.z - bf2f(h.z));
        h.w = f2bf(v.w); l.w = f2bf(v.w - bf2f(h.w));
        ((ushort4*)hi)[i] = h;
        ((ushort4*)lo)[i] = l;
    }
}

// ---------------------------------------------------------------------------
// gather emb rows per decoder token and split to (hi,lo) bf16: E[bt][DD]
// ---------------------------------------------------------------------------
__global__ void emb_gather_split(const int* __restrict__ targets,
                                 const float* __restrict__ emb,
                                 unsigned short* __restrict__ Eh,
                                 unsigned short* __restrict__ El) {
    long i = (long)blockIdx.x * 256 + threadIdx.x;   // one float4 per thread
    if (i >= (long)BB * TT * DD / 4) return;
    int row = (int)(i >> 7);            // DD/4 = 128 f4 per row
    int c4 = (int)(i & 127);
    int b = row / TT, t = row % TT;
    int tok = (t == 0) ? 1 : targets[b * TT + (t - 1)];
    float4 v = ((const float4*)(emb + (size_t)tok * DD))[c4];
    ushort4 h, l;
    h.x = f2bf(v.x); l.x = f2bf(v.x - bf2f(h.x));
    h.y = f2bf(v.y); l.y = f2bf(v.y - bf2f(h.y));
    h.z = f2bf(v.z); l.z = f2bf(v.z - bf2f(h.z));
    h.w = f2bf(v.w); l.w = f2bf(v.w - bf2f(h.w));
    ((ushort4*)Eh)[i] = h;
    ((ushort4*)El)[i] = l;
}

// ---------------------------------------------------------------------------
// Kernel A (mode2): xg via split-bf16 MFMA. M=1600, N=4096, K=512.
// Clone of the verified proj_mfma structure.
// ---------------------------------------------------------------------------
__global__ __launch_bounds__(256, 5) void xg_mfma(
    const unsigned short* __restrict__ Eh, const unsigned short* __restrict__ El,
    const unsigned short* __restrict__ Wih_h, const unsigned short* __restrict__ Wih_l,
    const float* __restrict__ b_ih, const float* __restrict__ b_hh,
    float* __restrict__ xg) {
    __shared__ __attribute__((aligned(16))) unsigned short sA[2][128 * 32];  // 16 KB
    __shared__ __attribute__((aligned(16))) unsigned short sB[2][128 * 32];  // 16 KB
    const int tid = threadIdx.x;
    const int w = tid >> 6;
    const int l = tid & 63;
    const int wr = w >> 1, wc = w & 1;
    const int lr = l & 15, lk = l >> 4;
    const int m0 = blockIdx.y * 128;
    const int n0 = blockIdx.x * 128;      // N=4096 exact, no clamp

    const unsigned short* garr = (w == 0) ? Eh : (w == 1) ? El
                               : (w == 2) ? Wih_h : Wih_l;
    unsigned short* larr = (w == 0) ? sA[0] : (w == 1) ? sA[1]
                         : (w == 2) ? sB[0] : sB[1];
    const int isA = (w < 2);
    const unsigned short* gsrc[8];
#pragma unroll
    for (int i = 0; i < 8; i++) {
        int r = i * 16 + (l >> 2);
        int sl = (l & 3) ^ ((r >> 1) & 3);
        int g = isA ? (m0 + r) : (n0 + r);
        if (isA && g > BB * TT - 1) g = BB * TT - 1;
        gsrc[i] = garr + (size_t)g * DD + sl * 8;
    }

    const int rswz = (lk ^ ((lr >> 1) & 3)) * 8;

    f32x4 acc[4][4];
#pragma unroll
    for (int i = 0; i < 4; i++)
#pragma unroll
        for (int j = 0; j < 4; j++) acc[i][j] = (f32x4){0.f, 0.f, 0.f, 0.f};

#pragma unroll 1
    for (int it = 0; it < 16; it++) {     // K=512 / BK=32
        const int k0v = it * 32;
#pragma unroll
        for (int i = 0; i < 8; i++)
            gl16(gsrc[i] + k0v, larr + i * 512);
        __syncthreads();

        bf16x8 ah[4], al[4], bh[4], bl[4];
#pragma unroll
        for (int i = 0; i < 4; i++) {
            int ra = (wr * 64 + i * 16 + lr) * 32 + rswz;
            ah[i] = *(const bf16x8*)&sA[0][ra];
            al[i] = *(const bf16x8*)&sA[1][ra];
        }
#pragma unroll
        for (int j = 0; j < 4; j++) {
            int rb = (wc * 64 + j * 16 + lr) * 32 + rswz;
            bh[j] = *(const bf16x8*)&sB[0][rb];
            bl[j] = *(const bf16x8*)&sB[1][rb];
        }
#pragma unroll
        for (int i = 0; i < 4; i++)
#pragma unroll
            for (int j = 0; j < 4; j++) {
                acc[i][j] = __builtin_amdgcn_mfma_f32_16x16x32_bf16(ah[i], bh[j], acc[i][j], 0, 0, 0);
                acc[i][j] = __builtin_amdgcn_mfma_f32_16x16x32_bf16(ah[i], bl[j], acc[i][j], 0, 0, 0);
                acc[i][j] = __builtin_amdgcn_mfma_f32_16x16x32_bf16(al[i], bh[j], acc[i][j], 0, 0, 0);
            }
        __syncthreads();
    }

    // epilogue: per-wave LDS transpose + contiguous row stores (bias fused)
    float* ewave = ((float*)sA) + w * 1024;
    const int nn = n0 + wc * 64 + l;
    const float bpv = b_ih[nn] + b_hh[nn];
#pragma unroll
    for (int i = 0; i < 4; i++) {
#pragma unroll
        for (int j = 0; j < 4; j++)
#pragma unroll
            for (int r2 = 0; r2 < 4; r2++)
                ewave[(lk * 4 + r2) * 64 + j * 16 + lr] = acc[i][j][r2];
#pragma unroll 1
        for (int rr = 0; rr < 16; rr++) {
            int m = m0 + wr * 64 + i * 16 + rr;
            float v = ewave[rr * 64 + l] + bpv;
            if (m < BB * TT)
                xg[(size_t)m * G4H + nn] = v;
        }
    }
}

// ---------------------------------------------------------------------------
// Kernel A-fallback: fp32 xg GEMM (modes 0/1)
// ---------------------------------------------------------------------------
__global__ void xg_gemm(const int* __restrict__ targets,
                        const float* __restrict__ emb,
                        const float* __restrict__ W_ih,
                        const float* __restrict__ b_ih,
                        const float* __restrict__ b_hh,
                        float* __restrict__ xg) {
    __shared__ float As[16][65];
    __shared__ float Bs[16][65];
    const int m0 = blockIdx.y * 64;
    const int n0 = blockIdx.x * 64;
    const int tid = threadIdx.x;
    const int tx = tid & 15;
    const int ty = tid >> 4;
    const int lk = tx;
    const int lm = ty;

    const float* arow[4];
    const float* brow[4];
#pragma unroll
    for (int i = 0; i < 4; i++) {
        int bt = m0 + lm + i * 16;
        int b = bt / TT, t = bt % TT;
        int tok = (t == 0) ? 1 : targets[b * TT + (t - 1)];
        arow[i] = emb + (size_t)tok * DD;
        int n = n0 + lm + i * 16;
        brow[i] = W_ih + (size_t)n * DD;
    }

    float acc[4][4] = {};
    for (int k0 = 0; k0 < DD; k0 += 16) {
#pragma unroll
        for (int i = 0; i < 4; i++) As[lk][lm + i * 16] = arow[i][k0 + lk];
#pragma unroll
        for (int i = 0; i < 4; i++) Bs[lk][lm + i * 16] = brow[i][k0 + lk];
        __syncthreads();
#pragma unroll
        for (int k = 0; k < 16; k++) {
            float a[4], bb[4];
#pragma unroll
            for (int i = 0; i < 4; i++) a[i] = As[k][ty + i * 16];
#pragma unroll
            for (int j = 0; j < 4; j++) bb[j] = Bs[k][tx + j * 16];
#pragma unroll
            for (int i = 0; i < 4; i++)
#pragma unroll
                for (int j = 0; j < 4; j++) acc[i][j] += a[i] * bb[j];
        }
        __syncthreads();
    }
#pragma unroll
    for (int i = 0; i < 4; i++) {
        int m = m0 + ty + i * 16;
#pragma unroll
        for (int j = 0; j < 4; j++) {
            int n = n0 + tx + j * 16;
            xg[(size_t)m * G4H + n] = acc[i][j] + b_ih[n] + b_hh[n];
        }
    }
}

// ---------------------------------------------------------------------------
// Kernel B (mode2): one LSTM step, SPLIT-K 8-wave (round-16, ~10.9 us/step).
// LDS 113KB -> 1 block/CU regardless; bound relaxed to (512,1) so the
// register allocator is unconstrained (uses ~88, cap now 256).
// ---------------------------------------------------------------------------
#define NH 16
__global__ __launch_bounds__(512, 1) void lstm_mfma(
    const unsigned short* __restrict__ Wh, const unsigned short* __restrict__ Wl,
    const float* __restrict__ xg,
    const unsigned short* __restrict__ hin_h, const unsigned short* __restrict__ hin_l,
    long hin_stride,
    float* __restrict__ c_buf,
    unsigned short* __restrict__ Ah, unsigned short* __restrict__ Al,
    int t) {
    __shared__ unsigned short sW[2][2][2][64 * 64];  // [half][buf][hl] 64 KB
    __shared__ unsigned short sH[2][2][2][32 * 64];  // [half][buf][hl] 32 KB
    __shared__ float gbuf[8][32][17];                // 17.4 KB
    const int tid = threadIdx.x;
    const int w = tid >> 6;
    const int g = w & 3;
    const int h2 = w >> 2;
    const int l = tid & 63;
    const int lr = l & 15, lk = l >> 4;
    const int nh0 = blockIdx.x * NH;

    const int stid = tid & 255;
    const int sh2 = tid >> 8;
    const int kbase = sh2 * 512;

    const int wrow = stid >> 2;
    const int ws0 = (stid & 3) * 2;
    const int wg = wrow >> 4, wj = wrow & 15;
    const unsigned short* gWh = Wh + (size_t)(wg * HH + nh0 + wj) * HH + kbase + ws0 * 8;
    const unsigned short* gWl = Wl + (size_t)(wg * HH + nh0 + wj) * HH + kbase + ws0 * 8;
    const int wwb0 = wrow * 64 + ((ws0) ^ (wrow & 7)) * 8;
    const int wwb1 = wrow * 64 + ((ws0 + 1) ^ (wrow & 7)) * 8;

    const int hp = stid & 127;
    const int hrow = hp >> 2;
    const int hs0 = (hp & 3) * 2;
    const unsigned short* gH =
        ((stid < 128) ? hin_h : hin_l) + (size_t)hrow * hin_stride + kbase + hs0 * 8;
    const int hsel = (stid < 128) ? 0 : 1;
    const int hwb0 = hrow * 64 + ((hs0) ^ (hrow & 7)) * 8;
    const int hwb1 = hrow * 64 + ((hs0 + 1) ^ (hrow & 7)) * 8;

    f32x4 acc0 = (f32x4){0.f, 0.f, 0.f, 0.f};
    f32x4 acc1 = (f32x4){0.f, 0.f, 0.f, 0.f};

    u16x8 rWh0 = *(const u16x8*)gWh, rWh1 = *(const u16x8*)(gWh + 8);
    u16x8 rWl0 = *(const u16x8*)gWl, rWl1 = *(const u16x8*)(gWl + 8);
    u16x8 rH0  = *(const u16x8*)gH,  rH1  = *(const u16x8*)(gH + 8);
    *(u16x8*)&sW[sh2][0][0][wwb0] = rWh0; *(u16x8*)&sW[sh2][0][0][wwb1] = rWh1;
    *(u16x8*)&sW[sh2][0][1][wwb0] = rWl0; *(u16x8*)&sW[sh2][0][1][wwb1] = rWl1;
    if (hsel == 0) { *(u16x8*)&sH[sh2][0][0][hwb0] = rH0; *(u16x8*)&sH[sh2][0][0][hwb1] = rH1; }
    else           { *(u16x8*)&sH[sh2][0][1][hwb0] = rH0; *(u16x8*)&sH[sh2][0][1][hwb1] = rH1; }
    rWh0 = *(const u16x8*)(gWh + 64); rWh1 = *(const u16x8*)(gWh + 64 + 8);
    rWl0 = *(const u16x8*)(gWl + 64); rWl1 = *(const u16x8*)(gWl + 64 + 8);
    rH0  = *(const u16x8*)(gH + 64);  rH1  = *(const u16x8*)(gH + 64 + 8);

    int cur = 0;
#pragma unroll 1
    for (int it = 0; it < 8; it++) {
        __syncthreads();
        if (it < 7) {
            const int nxt = cur ^ 1;
            *(u16x8*)&sW[sh2][nxt][0][wwb0] = rWh0; *(u16x8*)&sW[sh2][nxt][0][wwb1] = rWh1;
            *(u16x8*)&sW[sh2][nxt][1][wwb0] = rWl0; *(u16x8*)&sW[sh2][nxt][1][wwb1] = rWl1;
            if (hsel == 0) { *(u16x8*)&sH[sh2][nxt][0][hwb0] = rH0; *(u16x8*)&sH[sh2][nxt][0][hwb1] = rH1; }
            else           { *(u16x8*)&sH[sh2][nxt][1][hwb0] = rH0; *(u16x8*)&sH[sh2][nxt][1][hwb1] = rH1; }
            const int kn = (it < 6) ? (it + 2) * 64 : 0;
            rWh0 = *(const u16x8*)(gWh + kn); rWh1 = *(const u16x8*)(gWh + kn + 8);
            rWl0 = *(const u16x8*)(gWl + kn); rWl1 = *(const u16x8*)(gWl + kn + 8);
            rH0  = *(const u16x8*)(gH + kn);  rH1  = *(const u16x8*)(gH + kn + 8);
        }
#pragma unroll
        for (int kk = 0; kk < 2; kk++) {
            const int rsl = ((kk * 4 + lk) ^ (lr & 7)) * 8;
            bf16x8 bh = *(const bf16x8*)&sW[h2][cur][0][(g * 16 + lr) * 64 + rsl];
            bf16x8 bl = *(const bf16x8*)&sW[h2][cur][1][(g * 16 + lr) * 64 + rsl];
            bf16x8 a0h = *(const bf16x8*)&sH[h2][cur][0][lr * 64 + rsl];
            bf16x8 a1h = *(const bf16x8*)&sH[h2][cur][0][(16 + lr) * 64 + rsl];
            bf16x8 a0l = *(const bf16x8*)&sH[h2][cur][1][lr * 64 + rsl];
            bf16x8 a1l = *(const bf16x8*)&sH[h2][cur][1][(16 + lr) * 64 + rsl];
            acc0 = __builtin_amdgcn_mfma_f32_16x16x32_bf16(a0h, bh, acc0, 0, 0, 0);
            acc0 = __builtin_amdgcn_mfma_f32_16x16x32_bf16(a0h, bl, acc0, 0, 0, 0);
            acc0 = __builtin_amdgcn_mfma_f32_16x16x32_bf16(a0l, bh, acc0, 0, 0, 0);
            acc1 = __builtin_amdgcn_mfma_f32_16x16x32_bf16(a1h, bh, acc1, 0, 0, 0);
            acc1 = __builtin_amdgcn_mfma_f32_16x16x32_bf16(a1h, bl, acc1, 0, 0, 0);
            acc1 = __builtin_amdgcn_mfma_f32_16x16x32_bf16(a1l, bh, acc1, 0, 0, 0);
        }
        cur ^= 1;
    }

    __syncthreads();
#pragma unroll
    for (int r = 0; r < 4; r++) {
        gbuf[w][lk * 4 + r][lr] = acc0[r];
        gbuf[w][16 + lk * 4 + r][lr] = acc1[r];
    }
    __syncthreads();

    {
        int b = tid >> 4, j = tid & 15;
        size_t xb = ((size_t)b * TT + t) * G4H + nh0 + j;
        float gi_ = gbuf[0][b][j] + gbuf[4][b][j] + xg[xb];
        float gf_ = gbuf[1][b][j] + gbuf[5][b][j] + xg[xb + HH];
        float gg_ = gbuf[2][b][j] + gbuf[6][b][j] + xg[xb + 2 * HH];
        float go_ = gbuf[3][b][j] + gbuf[7][b][j] + xg[xb + 3 * HH];

        float i_ = 1.f / (1.f + expf(-gi_));
        float f_ = 1.f / (1.f + expf(-gf_));
        float g_ = tanhf(gg_);
        float o_ = 1.f / (1.f + expf(-go_));

        int ci = b * HH + nh0 + j;
        float c_old = (t == 0) ? 0.f : c_buf[ci];
        float c_new = f_ * c_old + i_ * g_;
        float h_new = o_ * tanhf(c_new);
        c_buf[ci] = c_new;

        size_t ho = ((size_t)b * TT + t) * HH + nh0 + j;
        unsigned short hh = f2bf(h_new);
        Ah[ho] = hh;
        Al[ho] = f2bf(h_new - bf2f(hh));
    }
}

// ---------------------------------------------------------------------------
// Kernel B-fallback: scalar-ish LSTM step (modes 0/1), float4 LDS
// ---------------------------------------------------------------------------
__global__ void lstm_step(const float* __restrict__ W_hh,
                          const float* __restrict__ xg,
                          const float* __restrict__ h_prev,
                          float* __restrict__ c_buf,
                          float* __restrict__ h_out,
                          float* __restrict__ hs_all,
                          int t) {
    __shared__ float h_s[32][68];
    __shared__ float w_s[32][68];
    const int tid = threadIdx.x;
    const int b = tid & 31;
    const int jl = tid >> 5;
    const int n0 = blockIdx.x * 8;
    const int n = n0 + jl;

    float acc[4] = {0.f, 0.f, 0.f, 0.f};
    for (int k0 = 0; k0 < HH; k0 += 64) {
#pragma unroll
        for (int i = 0; i < 2; i++) {
            int e = tid + i * 256;
            int r = e >> 4;
            int c = e & 15;
            float4 hv = *(const float4*)&h_prev[r * HH + k0 + c * 4];
            *(float4*)&h_s[r][c * 4] = hv;
            int gi = r >> 3, jj = r & 7;
            float4 wv = *(const float4*)&W_hh[(size_t)(gi * HH + n0 + jj) * HH + k0 + c * 4];
            *(float4*)&w_s[r][c * 4] = wv;
        }
        __syncthreads();
#pragma unroll
        for (int k = 0; k < 64; k += 4) {
            float4 hv = *(const float4*)&h_s[b][k];
            float4 w0 = *(const float4*)&w_s[jl][k];
            float4 w1 = *(const float4*)&w_s[8 + jl][k];
            float4 w2 = *(const float4*)&w_s[16 + jl][k];
            float4 w3 = *(const float4*)&w_s[24 + jl][k];
            acc[0] += hv.x * w0.x + hv.y * w0.y + hv.z * w0.z + hv.w * w0.w;
            acc[1] += hv.x * w1.x + hv.y * w1.y + hv.z * w1.z + hv.w * w1.w;
            acc[2] += hv.x * w2.x + hv.y * w2.y + hv.z * w2.z + hv.w * w2.w;
            acc[3] += hv.x * w3.x + hv.y * w3.y + hv.z * w3.z + hv.w * w3.w;
        }
        __syncthreads();
    }

    const int bt = b * TT + t;
    float gi_ = acc[0] + xg[(size_t)bt * G4H + n];
    float gf_ = acc[1] + xg[(size_t)bt * G4H + HH + n];
    float gg_ = acc[2] + xg[(size_t)bt * G4H + 2 * HH + n];
    float go_ = acc[3] + xg[(size_t)bt * G4H + 3 * HH + n];

    float i_ = 1.f / (1.f + expf(-gi_));
    float f_ = 1.f / (1.f + expf(-gf_));
    float g_ = tanhf(gg_);
    float o_ = 1.f / (1.f + expf(-go_));

    float c_old = (t == 0) ? 0.f : c_buf[b * HH + n];
    float c_new = f_ * c_old + i_ * g_;
    float h_new = o_ * tanhf(c_new);

    c_buf[b * HH + n] = c_new;
    h_out[b * HH + n] = h_new;
    hs_all[(size_t)bt * HH + n] = h_new;
}

// ---------------------------------------------------------------------------
// Kernel C: split-bf16 MFMA projection GEMM (round-14/16 body, 563 us).
// Only change: __launch_bounds__(256,5) — 32KB LDS permits 5 blocks/CU
// (5 x 32KB = 160KB exactly); old bound capped residency at 4.
// ---------------------------------------------------------------------------
__global__ __launch_bounds__(256, 5) void proj_mfma(
    const unsigned short* __restrict__ Ah, const unsigned short* __restrict__ Al,
    const unsigned short* __restrict__ Bh, const unsigned short* __restrict__ Bl,
    const float* __restrict__ b_proj, float* __restrict__ logits) {
    __shared__ __attribute__((aligned(16))) unsigned short sA[2][128 * 32];  // 16 KB
    __shared__ __attribute__((aligned(16))) unsigned short sB[2][128 * 32];  // 16 KB
    const int tid = threadIdx.x;
    const int w = tid >> 6;
    const int l = tid & 63;
    const int wr = w >> 1, wc = w & 1;
    const int lr = l & 15, lk = l >> 4;

    const int d = blockIdx.x;
    const int xcd = d & 7;
    const int k = d >> 3;
    const int ncnt = (xcd == 0) ? 50 : 49;
    const int nstart = (xcd == 0) ? 0 : 50 + (xcd - 1) * 49;
    if (k >= 13 * ncnt) return;
    const int per4 = 4 * ncnt;
    int s, rr_;
    if (k < per4)          { s = 0; rr_ = k; }
    else if (k < 2 * per4) { s = 1; rr_ = k - per4; }
    else if (k < 3 * per4) { s = 2; rr_ = k - 2 * per4; }
    else                   { s = 3; rr_ = k - 3 * per4; }
    const int ssize = (s == 3) ? 1 : 4;
    const int nloc = rr_ / ssize;
    const int mins = rr_ - nloc * ssize;
    const int m0 = (s * 4 + mins) * 128;
    const int n0 = (nstart + nloc) * 128;

    const unsigned short* garr = (w == 0) ? Ah : (w == 1) ? Al : (w == 2) ? Bh : Bl;
    unsigned short* larr = (w == 0) ? sA[0] : (w == 1) ? sA[1]
                         : (w == 2) ? sB[0] : sB[1];
    const int isA = (w < 2);
    const unsigned short* gsrc[8];
#pragma unroll
    for (int i = 0; i < 8; i++) {
        int r = i * 16 + (l >> 2);
        int sl = (l & 3) ^ ((r >> 1) & 3);
        int g = isA ? (m0 + r) : (n0 + r);
        int gmax = isA ? (BB * TT - 1) : (VV - 1);
        if (g > gmax) g = gmax;
        gsrc[i] = garr + (size_t)g * HH + sl * 8;
    }

    const int rswz = (lk ^ ((lr >> 1) & 3)) * 8;

    f32x4 acc[4][4];
#pragma unroll
    for (int i = 0; i < 4; i++)
#pragma unroll
        for (int j = 0; j < 4; j++) acc[i][j] = (f32x4){0.f, 0.f, 0.f, 0.f};

#pragma unroll 1
    for (int it = 0; it < 32; it++) {
        const int k0v = it * 32;
#pragma unroll
        for (int i = 0; i < 8; i++)
            gl16(gsrc[i] + k0v, larr + i * 512);
        __syncthreads();

        bf16x8 ah[4], al[4], bh[4], bl[4];
#pragma unroll
        for (int i = 0; i < 4; i++) {
            int ra = (wr * 64 + i * 16 + lr) * 32 + rswz;
            ah[i] = *(const bf16x8*)&sA[0][ra];
            al[i] = *(const bf16x8*)&sA[1][ra];
        }
#pragma unroll
        for (int j = 0; j < 4; j++) {
            int rb = (wc * 64 + j * 16 + lr) * 32 + rswz;
            bh[j] = *(const bf16x8*)&sB[0][rb];
            bl[j] = *(const bf16x8*)&sB[1][rb];
        }
#pragma unroll
        for (int i = 0; i < 4; i++)
#pragma unroll
            for (int j = 0; j < 4; j++) {
                acc[i][j] = __builtin_amdgcn_mfma_f32_16x16x32_bf16(ah[i], bh[j], acc[i][j], 0, 0, 0);
                acc[i][j] = __builtin_amdgcn_mfma_f32_16x16x32_bf16(ah[i], bl[j], acc[i][j], 0, 0, 0);
                acc[i][j] = __builtin_amdgcn_mfma_f32_16x16x32_bf16(al[i], bh[j], acc[i][j], 0, 0, 0);
            }
        __syncthreads();
    }

    float* ewave = ((float*)sA) + w * 1024;
    const int nn = n0 + wc * 64 + l;
    const float bpv = b_proj[nn < VV ? nn : VV - 1];
    const bool nok = (nn < VV);
#pragma unroll
    for (int i = 0; i < 4; i++) {
#pragma unroll
        for (int j = 0; j < 4; j++)
#pragma unroll
            for (int r2 = 0; r2 < 4; r2++)
                ewave[(lk * 4 + r2) * 64 + j * 16 + lr] = acc[i][j][r2];
#pragma unroll
        for (int rr = 0; rr < 16; rr++) {
            int m = m0 + wr * 64 + i * 16 + rr;
            float v = ewave[rr * 64 + l] + bpv;
            if (m < BB * TT && nok)
                logits[(size_t)m * VV + nn] = v;
        }
    }
}

// ---------------------------------------------------------------------------
// Kernel C-fallback: fp32 projection (mode 0 only)
// ---------------------------------------------------------------------------
__global__ void proj_gemm(const float* __restrict__ hs,
                          const float* __restrict__ W_proj,
                          const float* __restrict__ b_proj,
                          float* __restrict__ logits) {
    __shared__ float As[16][65];
    __shared__ float Bs[16][65];
    const int m0 = blockIdx.y * 64;
    const int n0 = blockIdx.x * 64;
    const int tid = threadIdx.x;
    const int tx = tid & 15;
    const int ty = tid >> 4;
    const int lk = tx;
    const int lm = ty;

    const float* arow[4];
    const float* brow[4];
    bool bval[4];
#pragma unroll
    for (int i = 0; i < 4; i++) {
        arow[i] = hs + (size_t)(m0 + lm + i * 16) * HH;
        int n = n0 + lm + i * 16;
        bval[i] = (n < VV);
        brow[i] = W_proj + (size_t)(bval[i] ? n : 0) * HH;
    }

    float acc[4][4] = {};
    for (int k0 = 0; k0 < HH; k0 += 16) {
#pragma unroll
        for (int i = 0; i < 4; i++) As[lk][lm + i * 16] = arow[i][k0 + lk];
#pragma unroll
        for (int i = 0; i < 4; i++)
            Bs[lk][lm + i * 16] = bval[i] ? brow[i][k0 + lk] : 0.f;
        __syncthreads();
#pragma unroll
        for (int k = 0; k < 16; k++) {
            float a[4], bb[4];
#pragma unroll
            for (int i = 0; i < 4; i++) a[i] = As[k][ty + i * 16];
#pragma unroll
            for (int j = 0; j < 4; j++) bb[j] = Bs[k][tx + j * 16];
#pragma unroll
            for (int i = 0; i < 4; i++)
#pragma unroll
                for (int j = 0; j < 4; j++) acc[i][j] += a[i] * bb[j];
        }
        __syncthreads();
    }
#pragma unroll
    for (int i = 0; i < 4; i++) {
        int m = m0 + ty + i * 16;
#pragma unroll
        for (int j = 0; j < 4; j++) {
            int n = n0 + tx + j * 16;
            if (n < VV)
                logits[(size_t)m * VV + n] = acc[i][j] + b_proj[n];
        }
    }
}

// ---------------------------------------------------------------------------
// Kernel D: argmax
// ---------------------------------------------------------------------------
__global__ void argmax_kernel(const float* __restrict__ logits,
                              float* __restrict__ preds) {
    const int bt = blockIdx.x;
    const float* row = logits + (size_t)bt * VV;
    const int tid = threadIdx.x;

    float best = -INFINITY;
    int bidx = 0x7fffffff;
    for (int v = tid; v < VV; v += 256) {
        float x = row[v];
        if (x > best) { best = x; bidx = v; }
    }
    __shared__ float sv[256];
    __shared__ int si[256];
    sv[tid] = best;
    si[tid] = bidx;
    __syncthreads();
    for (int s = 128; s > 0; s >>= 1) {
        if (tid < s) {
            float ov = sv[tid + s];
            int oi = si[tid + s];
            if (ov > sv[tid] || (ov == sv[tid] && oi < si[tid])) {
                sv[tid] = ov;
                si[tid] = oi;
            }
        }
        __syncthreads();
    }
    if (tid == 0) preds[bt] = (float)si[0];
}

// ---------------------------------------------------------------------------
extern "C" void kernel_launch(void* const* d_in, const int* in_sizes, int n_in,
                              void* d_out, int out_size, void* d_ws, size_t ws_size,
                              hipStream_t stream) {
    const float* inputs = (const float*)d_in[0];
    const int*   targets = (const int*)d_in[1];
    const float* emb    = (const float*)d_in[2];
    const float* W_ih   = (const float*)d_in[3];
    const float* W_hh   = (const float*)d_in[4];
    const float* b_ih   = (const float*)d_in[5];
    const float* b_hh   = (const float*)d_in[6];
    const float* W_proj = (const float*)d_in[7];
    const float* b_proj = (const float*)d_in[8];

    float* out = (float*)d_out;
    float* logits = out;
    float* preds = out + (size_t)BB * TT * VV;

    // ws layout: xg | cb | Ah | Al | Bh | Bl | R
    //   R: mode<=1 -> hs,h0,h1 fp32 ; mode2 -> Wh,Wl,iah,ial,Wih_h,Wih_l,Eh,El
    float* ws = (float*)d_ws;
    float* xg = ws;                                       // [B*T,4H] f32
    float* cb = xg + (size_t)BB * TT * G4H;               // [B,H] f32
    unsigned short* Ah = (unsigned short*)(cb + (size_t)BB * HH);
    unsigned short* Al = Ah + (size_t)BB * TT * HH;
    unsigned short* Bh = Al + (size_t)BB * TT * HH;
    unsigned short* Bl = Bh + (size_t)VV * HH;
    char* R = (char*)(Bl + (size_t)VV * HH);

    // mode<=1 view of R
    float* hs = (float*)R;                                // [B*T,H]
    float* h0 = hs + (size_t)BB * TT * HH;
    float* h1 = h0 + (size_t)BB * HH;
    // mode2 view of R
    unsigned short* Wh = (unsigned short*)R;              // [4H,H] bf16
    unsigned short* Wl = Wh + (size_t)G4H * HH;
    unsigned short* iah = Wl + (size_t)G4H * HH;          // [B,H] bf16
    unsigned short* ial = iah + (size_t)BB * HH;
    unsigned short* Wih_h = ial + (size_t)BB * HH;        // [4H,D] bf16
    unsigned short* Wih_l = Wih_h + (size_t)G4H * DD;
    unsigned short* Eh = Wih_l + (size_t)G4H * DD;        // [B*T,D] bf16
    unsigned short* El = Eh + (size_t)BB * TT * DD;

    size_t base = (char*)R - (char*)d_ws;
    size_t need1 = base + ((size_t)BB * TT * HH + 2 * (size_t)BB * HH) * 4;
    size_t need2 = base + (2 * (size_t)G4H * HH + 2 * (size_t)BB * HH
                         + 2 * (size_t)G4H * DD + 2 * (size_t)BB * TT * DD) * 2;
    int mode = (ws_size >= need2) ? 2 : (ws_size >= need1) ? 1 : 0;

    if (mode >= 1) {
        split_f32<<<4096, 256, 0, stream>>>(W_proj, Bh, Bl, (long)VV * HH / 4);
    }
    if (mode == 2) {
        split_f32<<<2048, 256, 0, stream>>>(W_hh, Wh, Wl, (long)G4H * HH / 4);
        split_f32<<<32, 256, 0, stream>>>(inputs, iah, ial, (long)BB * HH / 4);
        split_f32<<<1024, 256, 0, stream>>>(W_ih, Wih_h, Wih_l, (long)G4H * DD / 4);
        emb_gather_split<<<800, 256, 0, stream>>>(targets, emb, Eh, El);
        xg_mfma<<<dim3(32, 13), 256, 0, stream>>>(Eh, El, Wih_h, Wih_l,
                                                  b_ih, b_hh, xg);
    } else {
        xg_gemm<<<dim3(64, 25), 256, 0, stream>>>(targets, emb, W_ih, b_ih, b_hh, xg);
    }

    if (mode == 2) {
        for (int t = 0; t < TT; t++) {
            const unsigned short* hh = (t == 0) ? iah : (Ah + (size_t)(t - 1) * HH);
            const unsigned short* hl = (t == 0) ? ial : (Al + (size_t)(t - 1) * HH);
            long hstride = (t == 0) ? HH : (long)TT * HH;
            lstm_mfma<<<64, 512, 0, stream>>>(Wh, Wl, xg, hh, hl, hstride,
                                              cb, Ah, Al, t);
        }
        proj_mfma<<<5200, 256, 0, stream>>>(Ah, Al, Bh, Bl, b_proj, logits);
    } else {
        for (int t = 0; t < TT; t++) {
            const float* hp = (t == 0) ? inputs : ((t & 1) ? h0 : h1);
            float* ho = (t & 1) ? h1 : h0;
            lstm_step<<<128, 256, 0, stream>>>(W_hh, xg, hp, cb, ho, hs, t);
        }
        if (mode == 1) {
            split_f32<<<1600, 256, 0, stream>>>(hs, Ah, Al, (long)BB * TT * HH / 4);
            proj_mfma<<<5200, 256, 0, stream>>>(Ah, Al, Bh, Bl, b_proj, logits);
        } else {
            proj_gemm<<<dim3(786, 25), 256, 0, stream>>>(hs, W_proj, b_proj, logits);
        }
    }

    argmax_kernel<<<1600, 256, 0, stream>>>(logits, preds);
}

// Round 21
// 1183.004 us; speedup vs baseline: 2.0034x; 2.0034x over previous
//
#include <hip/hip_runtime.h>
#include <math.h>

#define BB 32
#define TT 50
#define HH 1024
#define DD 512
#define VV 50257
#define G4H 4096

typedef __attribute__((ext_vector_type(8))) short bf16x8;           // 8 bf16 in 4 VGPRs
typedef __attribute__((ext_vector_type(8))) unsigned short u16x8;   // staging vec
typedef __attribute__((ext_vector_type(4))) float f32x4;

__device__ inline unsigned short f2bf(float x) {
    unsigned u = __float_as_uint(x);
    u = (u + 0x7fff + ((u >> 16) & 1)) >> 16;   // RNE
    return (unsigned short)u;
}
__device__ inline float bf2f(unsigned short h) {
    return __uint_as_float(((unsigned)h) << 16);
}
__device__ inline void gl16(const void* g, void* l) {
    __builtin_amdgcn_global_load_lds(
        (const __attribute__((address_space(1))) unsigned int*)g,
        (__attribute__((address_space(3))) unsigned int*)l, 16, 0, 0);
}

// ---------------------------------------------------------------------------
// split fp32 -> (hi, lo) bf16 pair, vectorized x4
// ---------------------------------------------------------------------------
__global__ void split_f32(const float* __restrict__ x,
                          unsigned short* __restrict__ hi,
                          unsigned short* __restrict__ lo, long n4) {
    long i = (long)blockIdx.x * 256 + threadIdx.x;
    long stride = (long)gridDim.x * 256;
    for (; i < n4; i += stride) {
        float4 v = ((const float4*)x)[i];
        ushort4 h, l;
        h.x = f2bf(v.x); l.x = f2bf(v.x - bf2f(h.x));
        h.y = f2bf(v.y); l.y = f2bf(v.y - bf2f(h.y));
        h.z = f2bf(v.z); l.z = f2bf(v.z - bf2f(h.z));
        h.w = f2bf(v.w); l.w = f2bf(v.w - bf2f(h.w));
        ((ushort4*)hi)[i] = h;
        ((ushort4*)lo)[i] = l;
    }
}

// ---------------------------------------------------------------------------
// gather emb rows per decoder token and split to (hi,lo) bf16: E[bt][DD]
// ---------------------------------------------------------------------------
__global__ void emb_gather_split(const int* __restrict__ targets,
                                 const float* __restrict__ emb,
                                 unsigned short* __restrict__ Eh,
                                 unsigned short* __restrict__ El) {
    long i = (long)blockIdx.x * 256 + threadIdx.x;   // one float4 per thread
    if (i >= (long)BB * TT * DD / 4) return;
    int row = (int)(i >> 7);            // DD/4 = 128 f4 per row
    int c4 = (int)(i & 127);
    int b = row / TT, t = row % TT;
    int tok = (t == 0) ? 1 : targets[b * TT + (t - 1)];
    float4 v = ((const float4*)(emb + (size_t)tok * DD))[c4];
    ushort4 h, l;
    h.x = f2bf(v.x); l.x = f2bf(v.x - bf2f(h.x));
    h.y = f2bf(v.y); l.y = f2bf(v.y - bf2f(h.y));
    h.z = f2bf(v.z); l.z = f2bf(v.z - bf2f(h.z));
    h.w = f2bf(v.w); l.w = f2bf(v.w - bf2f(h.w));
    ((ushort4*)Eh)[i] = h;
    ((ushort4*)El)[i] = l;
}

// ---------------------------------------------------------------------------
// Kernel A (mode2): xg via split-bf16 MFMA. M=1600, N=4096, K=512.
// Clone of the verified proj_mfma structure. (256,4): 4 was measured-good;
// 5 forced VGPR 64->48 and spilled accumulators (round-20 regression).
// ---------------------------------------------------------------------------
__global__ __launch_bounds__(256, 4) void xg_mfma(
    const unsigned short* __restrict__ Eh, const unsigned short* __restrict__ El,
    const unsigned short* __restrict__ Wih_h, const unsigned short* __restrict__ Wih_l,
    const float* __restrict__ b_ih, const float* __restrict__ b_hh,
    float* __restrict__ xg) {
    __shared__ __attribute__((aligned(16))) unsigned short sA[2][128 * 32];  // 16 KB
    __shared__ __attribute__((aligned(16))) unsigned short sB[2][128 * 32];  // 16 KB
    const int tid = threadIdx.x;
    const int w = tid >> 6;
    const int l = tid & 63;
    const int wr = w >> 1, wc = w & 1;
    const int lr = l & 15, lk = l >> 4;
    const int m0 = blockIdx.y * 128;
    const int n0 = blockIdx.x * 128;      // N=4096 exact, no clamp

    const unsigned short* garr = (w == 0) ? Eh : (w == 1) ? El
                               : (w == 2) ? Wih_h : Wih_l;
    unsigned short* larr = (w == 0) ? sA[0] : (w == 1) ? sA[1]
                         : (w == 2) ? sB[0] : sB[1];
    const int isA = (w < 2);
    const unsigned short* gsrc[8];
#pragma unroll
    for (int i = 0; i < 8; i++) {
        int r = i * 16 + (l >> 2);
        int sl = (l & 3) ^ ((r >> 1) & 3);
        int g = isA ? (m0 + r) : (n0 + r);
        if (isA && g > BB * TT - 1) g = BB * TT - 1;
        gsrc[i] = garr + (size_t)g * DD + sl * 8;
    }

    const int rswz = (lk ^ ((lr >> 1) & 3)) * 8;

    f32x4 acc[4][4];
#pragma unroll
    for (int i = 0; i < 4; i++)
#pragma unroll
        for (int j = 0; j < 4; j++) acc[i][j] = (f32x4){0.f, 0.f, 0.f, 0.f};

#pragma unroll 1
    for (int it = 0; it < 16; it++) {     // K=512 / BK=32
        const int k0v = it * 32;
#pragma unroll
        for (int i = 0; i < 8; i++)
            gl16(gsrc[i] + k0v, larr + i * 512);
        __syncthreads();

        bf16x8 ah[4], al[4], bh[4], bl[4];
#pragma unroll
        for (int i = 0; i < 4; i++) {
            int ra = (wr * 64 + i * 16 + lr) * 32 + rswz;
            ah[i] = *(const bf16x8*)&sA[0][ra];
            al[i] = *(const bf16x8*)&sA[1][ra];
        }
#pragma unroll
        for (int j = 0; j < 4; j++) {
            int rb = (wc * 64 + j * 16 + lr) * 32 + rswz;
            bh[j] = *(const bf16x8*)&sB[0][rb];
            bl[j] = *(const bf16x8*)&sB[1][rb];
        }
#pragma unroll
        for (int i = 0; i < 4; i++)
#pragma unroll
            for (int j = 0; j < 4; j++) {
                acc[i][j] = __builtin_amdgcn_mfma_f32_16x16x32_bf16(ah[i], bh[j], acc[i][j], 0, 0, 0);
                acc[i][j] = __builtin_amdgcn_mfma_f32_16x16x32_bf16(ah[i], bl[j], acc[i][j], 0, 0, 0);
                acc[i][j] = __builtin_amdgcn_mfma_f32_16x16x32_bf16(al[i], bh[j], acc[i][j], 0, 0, 0);
            }
        __syncthreads();
    }

    // epilogue: per-wave LDS transpose + contiguous row stores (bias fused)
    float* ewave = ((float*)sA) + w * 1024;
    const int nn = n0 + wc * 64 + l;
    const float bpv = b_ih[nn] + b_hh[nn];
#pragma unroll
    for (int i = 0; i < 4; i++) {
#pragma unroll
        for (int j = 0; j < 4; j++)
#pragma unroll
            for (int r2 = 0; r2 < 4; r2++)
                ewave[(lk * 4 + r2) * 64 + j * 16 + lr] = acc[i][j][r2];
#pragma unroll 1
        for (int rr = 0; rr < 16; rr++) {
            int m = m0 + wr * 64 + i * 16 + rr;
            float v = ewave[rr * 64 + l] + bpv;
            if (m < BB * TT)
                xg[(size_t)m * G4H + nn] = v;
        }
    }
}

// ---------------------------------------------------------------------------
// Kernel A-fallback: fp32 xg GEMM (modes 0/1)
// ---------------------------------------------------------------------------
__global__ void xg_gemm(const int* __restrict__ targets,
                        const float* __restrict__ emb,
                        const float* __restrict__ W_ih,
                        const float* __restrict__ b_ih,
                        const float* __restrict__ b_hh,
                        float* __restrict__ xg) {
    __shared__ float As[16][65];
    __shared__ float Bs[16][65];
    const int m0 = blockIdx.y * 64;
    const int n0 = blockIdx.x * 64;
    const int tid = threadIdx.x;
    const int tx = tid & 15;
    const int ty = tid >> 4;
    const int lk = tx;
    const int lm = ty;

    const float* arow[4];
    const float* brow[4];
#pragma unroll
    for (int i = 0; i < 4; i++) {
        int bt = m0 + lm + i * 16;
        int b = bt / TT, t = bt % TT;
        int tok = (t == 0) ? 1 : targets[b * TT + (t - 1)];
        arow[i] = emb + (size_t)tok * DD;
        int n = n0 + lm + i * 16;
        brow[i] = W_ih + (size_t)n * DD;
    }

    float acc[4][4] = {};
    for (int k0 = 0; k0 < DD; k0 += 16) {
#pragma unroll
        for (int i = 0; i < 4; i++) As[lk][lm + i * 16] = arow[i][k0 + lk];
#pragma unroll
        for (int i = 0; i < 4; i++) Bs[lk][lm + i * 16] = brow[i][k0 + lk];
        __syncthreads();
#pragma unroll
        for (int k = 0; k < 16; k++) {
            float a[4], bb[4];
#pragma unroll
            for (int i = 0; i < 4; i++) a[i] = As[k][ty + i * 16];
#pragma unroll
            for (int j = 0; j < 4; j++) bb[j] = Bs[k][tx + j * 16];
#pragma unroll
            for (int i = 0; i < 4; i++)
#pragma unroll
                for (int j = 0; j < 4; j++) acc[i][j] += a[i] * bb[j];
        }
        __syncthreads();
    }
#pragma unroll
    for (int i = 0; i < 4; i++) {
        int m = m0 + ty + i * 16;
#pragma unroll
        for (int j = 0; j < 4; j++) {
            int n = n0 + tx + j * 16;
            xg[(size_t)m * G4H + n] = acc[i][j] + b_ih[n] + b_hh[n];
        }
    }
}

// ---------------------------------------------------------------------------
// Kernel B (mode2): one LSTM step, SPLIT-K 8-wave (round-16, ~10.9 us/step)
// ---------------------------------------------------------------------------
#define NH 16
__global__ __launch_bounds__(512, 2) void lstm_mfma(
    const unsigned short* __restrict__ Wh, const unsigned short* __restrict__ Wl,
    const float* __restrict__ xg,
    const unsigned short* __restrict__ hin_h, const unsigned short* __restrict__ hin_l,
    long hin_stride,
    float* __restrict__ c_buf,
    unsigned short* __restrict__ Ah, unsigned short* __restrict__ Al,
    int t) {
    __shared__ unsigned short sW[2][2][2][64 * 64];  // [half][buf][hl] 64 KB
    __shared__ unsigned short sH[2][2][2][32 * 64];  // [half][buf][hl] 32 KB
    __shared__ float gbuf[8][32][17];                // 17.4 KB
    const int tid = threadIdx.x;
    const int w = tid >> 6;
    const int g = w & 3;
    const int h2 = w >> 2;
    const int l = tid & 63;
    const int lr = l & 15, lk = l >> 4;
    const int nh0 = blockIdx.x * NH;

    const int stid = tid & 255;
    const int sh2 = tid >> 8;
    const int kbase = sh2 * 512;

    const int wrow = stid >> 2;
    const int ws0 = (stid & 3) * 2;
    const int wg = wrow >> 4, wj = wrow & 15;
    const unsigned short* gWh = Wh + (size_t)(wg * HH + nh0 + wj) * HH + kbase + ws0 * 8;
    const unsigned short* gWl = Wl + (size_t)(wg * HH + nh0 + wj) * HH + kbase + ws0 * 8;
    const int wwb0 = wrow * 64 + ((ws0) ^ (wrow & 7)) * 8;
    const int wwb1 = wrow * 64 + ((ws0 + 1) ^ (wrow & 7)) * 8;

    const int hp = stid & 127;
    const int hrow = hp >> 2;
    const int hs0 = (hp & 3) * 2;
    const unsigned short* gH =
        ((stid < 128) ? hin_h : hin_l) + (size_t)hrow * hin_stride + kbase + hs0 * 8;
    const int hsel = (stid < 128) ? 0 : 1;
    const int hwb0 = hrow * 64 + ((hs0) ^ (hrow & 7)) * 8;
    const int hwb1 = hrow * 64 + ((hs0 + 1) ^ (hrow & 7)) * 8;

    f32x4 acc0 = (f32x4){0.f, 0.f, 0.f, 0.f};
    f32x4 acc1 = (f32x4){0.f, 0.f, 0.f, 0.f};

    u16x8 rWh0 = *(const u16x8*)gWh, rWh1 = *(const u16x8*)(gWh + 8);
    u16x8 rWl0 = *(const u16x8*)gWl, rWl1 = *(const u16x8*)(gWl + 8);
    u16x8 rH0  = *(const u16x8*)gH,  rH1  = *(const u16x8*)(gH + 8);
    *(u16x8*)&sW[sh2][0][0][wwb0] = rWh0; *(u16x8*)&sW[sh2][0][0][wwb1] = rWh1;
    *(u16x8*)&sW[sh2][0][1][wwb0] = rWl0; *(u16x8*)&sW[sh2][0][1][wwb1] = rWl1;
    if (hsel == 0) { *(u16x8*)&sH[sh2][0][0][hwb0] = rH0; *(u16x8*)&sH[sh2][0][0][hwb1] = rH1; }
    else           { *(u16x8*)&sH[sh2][0][1][hwb0] = rH0; *(u16x8*)&sH[sh2][0][1][hwb1] = rH1; }
    rWh0 = *(const u16x8*)(gWh + 64); rWh1 = *(const u16x8*)(gWh + 64 + 8);
    rWl0 = *(const u16x8*)(gWl + 64); rWl1 = *(const u16x8*)(gWl + 64 + 8);
    rH0  = *(const u16x8*)(gH + 64);  rH1  = *(const u16x8*)(gH + 64 + 8);

    int cur = 0;
#pragma unroll 1
    for (int it = 0; it < 8; it++) {
        __syncthreads();
        if (it < 7) {
            const int nxt = cur ^ 1;
            *(u16x8*)&sW[sh2][nxt][0][wwb0] = rWh0; *(u16x8*)&sW[sh2][nxt][0][wwb1] = rWh1;
            *(u16x8*)&sW[sh2][nxt][1][wwb0] = rWl0; *(u16x8*)&sW[sh2][nxt][1][wwb1] = rWl1;
            if (hsel == 0) { *(u16x8*)&sH[sh2][nxt][0][hwb0] = rH0; *(u16x8*)&sH[sh2][nxt][0][hwb1] = rH1; }
            else           { *(u16x8*)&sH[sh2][nxt][1][hwb0] = rH0; *(u16x8*)&sH[sh2][nxt][1][hwb1] = rH1; }
            const int kn = (it < 6) ? (it + 2) * 64 : 0;
            rWh0 = *(const u16x8*)(gWh + kn); rWh1 = *(const u16x8*)(gWh + kn + 8);
            rWl0 = *(const u16x8*)(gWl + kn); rWl1 = *(const u16x8*)(gWl + kn + 8);
            rH0  = *(const u16x8*)(gH + kn);  rH1  = *(const u16x8*)(gH + kn + 8);
        }
#pragma unroll
        for (int kk = 0; kk < 2; kk++) {
            const int rsl = ((kk * 4 + lk) ^ (lr & 7)) * 8;
            bf16x8 bh = *(const bf16x8*)&sW[h2][cur][0][(g * 16 + lr) * 64 + rsl];
            bf16x8 bl = *(const bf16x8*)&sW[h2][cur][1][(g * 16 + lr) * 64 + rsl];
            bf16x8 a0h = *(const bf16x8*)&sH[h2][cur][0][lr * 64 + rsl];
            bf16x8 a1h = *(const bf16x8*)&sH[h2][cur][0][(16 + lr) * 64 + rsl];
            bf16x8 a0l = *(const bf16x8*)&sH[h2][cur][1][lr * 64 + rsl];
            bf16x8 a1l = *(const bf16x8*)&sH[h2][cur][1][(16 + lr) * 64 + rsl];
            acc0 = __builtin_amdgcn_mfma_f32_16x16x32_bf16(a0h, bh, acc0, 0, 0, 0);
            acc0 = __builtin_amdgcn_mfma_f32_16x16x32_bf16(a0h, bl, acc0, 0, 0, 0);
            acc0 = __builtin_amdgcn_mfma_f32_16x16x32_bf16(a0l, bh, acc0, 0, 0, 0);
            acc1 = __builtin_amdgcn_mfma_f32_16x16x32_bf16(a1h, bh, acc1, 0, 0, 0);
            acc1 = __builtin_amdgcn_mfma_f32_16x16x32_bf16(a1h, bl, acc1, 0, 0, 0);
            acc1 = __builtin_amdgcn_mfma_f32_16x16x32_bf16(a1l, bh, acc1, 0, 0, 0);
        }
        cur ^= 1;
    }

    __syncthreads();
#pragma unroll
    for (int r = 0; r < 4; r++) {
        gbuf[w][lk * 4 + r][lr] = acc0[r];
        gbuf[w][16 + lk * 4 + r][lr] = acc1[r];
    }
    __syncthreads();

    {
        int b = tid >> 4, j = tid & 15;
        size_t xb = ((size_t)b * TT + t) * G4H + nh0 + j;
        float gi_ = gbuf[0][b][j] + gbuf[4][b][j] + xg[xb];
        float gf_ = gbuf[1][b][j] + gbuf[5][b][j] + xg[xb + HH];
        float gg_ = gbuf[2][b][j] + gbuf[6][b][j] + xg[xb + 2 * HH];
        float go_ = gbuf[3][b][j] + gbuf[7][b][j] + xg[xb + 3 * HH];

        float i_ = 1.f / (1.f + expf(-gi_));
        float f_ = 1.f / (1.f + expf(-gf_));
        float g_ = tanhf(gg_);
        float o_ = 1.f / (1.f + expf(-go_));

        int ci = b * HH + nh0 + j;
        float c_old = (t == 0) ? 0.f : c_buf[ci];
        float c_new = f_ * c_old + i_ * g_;
        float h_new = o_ * tanhf(c_new);
        c_buf[ci] = c_new;

        size_t ho = ((size_t)b * TT + t) * HH + nh0 + j;
        unsigned short hh = f2bf(h_new);
        Ah[ho] = hh;
        Al[ho] = f2bf(h_new - bf2f(hh));
    }
}

// ---------------------------------------------------------------------------
// Kernel B-fallback: scalar-ish LSTM step (modes 0/1), float4 LDS
// ---------------------------------------------------------------------------
__global__ void lstm_step(const float* __restrict__ W_hh,
                          const float* __restrict__ xg,
                          const float* __restrict__ h_prev,
                          float* __restrict__ c_buf,
                          float* __restrict__ h_out,
                          float* __restrict__ hs_all,
                          int t) {
    __shared__ float h_s[32][68];
    __shared__ float w_s[32][68];
    const int tid = threadIdx.x;
    const int b = tid & 31;
    const int jl = tid >> 5;
    const int n0 = blockIdx.x * 8;
    const int n = n0 + jl;

    float acc[4] = {0.f, 0.f, 0.f, 0.f};
    for (int k0 = 0; k0 < HH; k0 += 64) {
#pragma unroll
        for (int i = 0; i < 2; i++) {
            int e = tid + i * 256;
            int r = e >> 4;
            int c = e & 15;
            float4 hv = *(const float4*)&h_prev[r * HH + k0 + c * 4];
            *(float4*)&h_s[r][c * 4] = hv;
            int gi = r >> 3, jj = r & 7;
            float4 wv = *(const float4*)&W_hh[(size_t)(gi * HH + n0 + jj) * HH + k0 + c * 4];
            *(float4*)&w_s[r][c * 4] = wv;
        }
        __syncthreads();
#pragma unroll
        for (int k = 0; k < 64; k += 4) {
            float4 hv = *(const float4*)&h_s[b][k];
            float4 w0 = *(const float4*)&w_s[jl][k];
            float4 w1 = *(const float4*)&w_s[8 + jl][k];
            float4 w2 = *(const float4*)&w_s[16 + jl][k];
            float4 w3 = *(const float4*)&w_s[24 + jl][k];
            acc[0] += hv.x * w0.x + hv.y * w0.y + hv.z * w0.z + hv.w * w0.w;
            acc[1] += hv.x * w1.x + hv.y * w1.y + hv.z * w1.z + hv.w * w1.w;
            acc[2] += hv.x * w2.x + hv.y * w2.y + hv.z * w2.z + hv.w * w2.w;
            acc[3] += hv.x * w3.x + hv.y * w3.y + hv.z * w3.z + hv.w * w3.w;
        }
        __syncthreads();
    }

    const int bt = b * TT + t;
    float gi_ = acc[0] + xg[(size_t)bt * G4H + n];
    float gf_ = acc[1] + xg[(size_t)bt * G4H + HH + n];
    float gg_ = acc[2] + xg[(size_t)bt * G4H + 2 * HH + n];
    float go_ = acc[3] + xg[(size_t)bt * G4H + 3 * HH + n];

    float i_ = 1.f / (1.f + expf(-gi_));
    float f_ = 1.f / (1.f + expf(-gf_));
    float g_ = tanhf(gg_);
    float o_ = 1.f / (1.f + expf(-go_));

    float c_old = (t == 0) ? 0.f : c_buf[b * HH + n];
    float c_new = f_ * c_old + i_ * g_;
    float h_new = o_ * tanhf(c_new);

    c_buf[b * HH + n] = c_new;
    h_out[b * HH + n] = h_new;
    hs_all[(size_t)bt * HH + n] = h_new;
}

// ---------------------------------------------------------------------------
// Kernel C: split-bf16 MFMA projection GEMM (round-14/16/19 body, 563 us,
// 878 TF effective = m97-structure ceiling). (256,4) is load-bearing:
// (256,5) forced VGPR 64->48 and spilled accumulators (round 20).
// ---------------------------------------------------------------------------
__global__ __launch_bounds__(256, 4) void proj_mfma(
    const unsigned short* __restrict__ Ah, const unsigned short* __restrict__ Al,
    const unsigned short* __restrict__ Bh, const unsigned short* __restrict__ Bl,
    const float* __restrict__ b_proj, float* __restrict__ logits) {
    __shared__ __attribute__((aligned(16))) unsigned short sA[2][128 * 32];  // 16 KB
    __shared__ __attribute__((aligned(16))) unsigned short sB[2][128 * 32];  // 16 KB
    const int tid = threadIdx.x;
    const int w = tid >> 6;
    const int l = tid & 63;
    const int wr = w >> 1, wc = w & 1;
    const int lr = l & 15, lk = l >> 4;

    const int d = blockIdx.x;
    const int xcd = d & 7;
    const int k = d >> 3;
    const int ncnt = (xcd == 0) ? 50 : 49;
    const int nstart = (xcd == 0) ? 0 : 50 + (xcd - 1) * 49;
    if (k >= 13 * ncnt) return;
    const int per4 = 4 * ncnt;
    int s, rr_;
    if (k < per4)          { s = 0; rr_ = k; }
    else if (k < 2 * per4) { s = 1; rr_ = k - per4; }
    else if (k < 3 * per4) { s = 2; rr_ = k - 2 * per4; }
    else                   { s = 3; rr_ = k - 3 * per4; }
    const int ssize = (s == 3) ? 1 : 4;
    const int nloc = rr_ / ssize;
    const int mins = rr_ - nloc * ssize;
    const int m0 = (s * 4 + mins) * 128;
    const int n0 = (nstart + nloc) * 128;

    const unsigned short* garr = (w == 0) ? Ah : (w == 1) ? Al : (w == 2) ? Bh : Bl;
    unsigned short* larr = (w == 0) ? sA[0] : (w == 1) ? sA[1]
                         : (w == 2) ? sB[0] : sB[1];
    const int isA = (w < 2);
    const unsigned short* gsrc[8];
#pragma unroll
    for (int i = 0; i < 8; i++) {
        int r = i * 16 + (l >> 2);
        int sl = (l & 3) ^ ((r >> 1) & 3);
        int g = isA ? (m0 + r) : (n0 + r);
        int gmax = isA ? (BB * TT - 1) : (VV - 1);
        if (g > gmax) g = gmax;
        gsrc[i] = garr + (size_t)g * HH + sl * 8;
    }

    const int rswz = (lk ^ ((lr >> 1) & 3)) * 8;

    f32x4 acc[4][4];
#pragma unroll
    for (int i = 0; i < 4; i++)
#pragma unroll
        for (int j = 0; j < 4; j++) acc[i][j] = (f32x4){0.f, 0.f, 0.f, 0.f};

#pragma unroll 1
    for (int it = 0; it < 32; it++) {
        const int k0v = it * 32;
#pragma unroll
        for (int i = 0; i < 8; i++)
            gl16(gsrc[i] + k0v, larr + i * 512);
        __syncthreads();

        bf16x8 ah[4], al[4], bh[4], bl[4];
#pragma unroll
        for (int i = 0; i < 4; i++) {
            int ra = (wr * 64 + i * 16 + lr) * 32 + rswz;
            ah[i] = *(const bf16x8*)&sA[0][ra];
            al[i] = *(const bf16x8*)&sA[1][ra];
        }
#pragma unroll
        for (int j = 0; j < 4; j++) {
            int rb = (wc * 64 + j * 16 + lr) * 32 + rswz;
            bh[j] = *(const bf16x8*)&sB[0][rb];
            bl[j] = *(const bf16x8*)&sB[1][rb];
        }
#pragma unroll
        for (int i = 0; i < 4; i++)
#pragma unroll
            for (int j = 0; j < 4; j++) {
                acc[i][j] = __builtin_amdgcn_mfma_f32_16x16x32_bf16(ah[i], bh[j], acc[i][j], 0, 0, 0);
                acc[i][j] = __builtin_amdgcn_mfma_f32_16x16x32_bf16(ah[i], bl[j], acc[i][j], 0, 0, 0);
                acc[i][j] = __builtin_amdgcn_mfma_f32_16x16x32_bf16(al[i], bh[j], acc[i][j], 0, 0, 0);
            }
        __syncthreads();
    }

    float* ewave = ((float*)sA) + w * 1024;
    const int nn = n0 + wc * 64 + l;
    const float bpv = b_proj[nn < VV ? nn : VV - 1];
    const bool nok = (nn < VV);
#pragma unroll
    for (int i = 0; i < 4; i++) {
#pragma unroll
        for (int j = 0; j < 4; j++)
#pragma unroll
            for (int r2 = 0; r2 < 4; r2++)
                ewave[(lk * 4 + r2) * 64 + j * 16 + lr] = acc[i][j][r2];
#pragma unroll
        for (int rr = 0; rr < 16; rr++) {
            int m = m0 + wr * 64 + i * 16 + rr;
            float v = ewave[rr * 64 + l] + bpv;
            if (m < BB * TT && nok)
                logits[(size_t)m * VV + nn] = v;
        }
    }
}

// ---------------------------------------------------------------------------
// Kernel C-fallback: fp32 projection (mode 0 only)
// ---------------------------------------------------------------------------
__global__ void proj_gemm(const float* __restrict__ hs,
                          const float* __restrict__ W_proj,
                          const float* __restrict__ b_proj,
                          float* __restrict__ logits) {
    __shared__ float As[16][65];
    __shared__ float Bs[16][65];
    const int m0 = blockIdx.y * 64;
    const int n0 = blockIdx.x * 64;
    const int tid = threadIdx.x;
    const int tx = tid & 15;
    const int ty = tid >> 4;
    const int lk = tx;
    const int lm = ty;

    const float* arow[4];
    const float* brow[4];
    bool bval[4];
#pragma unroll
    for (int i = 0; i < 4; i++) {
        arow[i] = hs + (size_t)(m0 + lm + i * 16) * HH;
        int n = n0 + lm + i * 16;
        bval[i] = (n < VV);
        brow[i] = W_proj + (size_t)(bval[i] ? n : 0) * HH;
    }

    float acc[4][4] = {};
    for (int k0 = 0; k0 < HH; k0 += 16) {
#pragma unroll
        for (int i = 0; i < 4; i++) As[lk][lm + i * 16] = arow[i][k0 + lk];
#pragma unroll
        for (int i = 0; i < 4; i++)
            Bs[lk][lm + i * 16] = bval[i] ? brow[i][k0 + lk] : 0.f;
        __syncthreads();
#pragma unroll
        for (int k = 0; k < 16; k++) {
            float a[4], bb[4];
#pragma unroll
            for (int i = 0; i < 4; i++) a[i] = As[k][ty + i * 16];
#pragma unroll
            for (int j = 0; j < 4; j++) bb[j] = Bs[k][tx + j * 16];
#pragma unroll
            for (int i = 0; i < 4; i++)
#pragma unroll
                for (int j = 0; j < 4; j++) acc[i][j] += a[i] * bb[j];
        }
        __syncthreads();
    }
#pragma unroll
    for (int i = 0; i < 4; i++) {
        int m = m0 + ty + i * 16;
#pragma unroll
        for (int j = 0; j < 4; j++) {
            int n = n0 + tx + j * 16;
            if (n < VV)
                logits[(size_t)m * VV + n] = acc[i][j] + b_proj[n];
        }
    }
}

// ---------------------------------------------------------------------------
// Kernel D: argmax
// ---------------------------------------------------------------------------
__global__ void argmax_kernel(const float* __restrict__ logits,
                              float* __restrict__ preds) {
    const int bt = blockIdx.x;
    const float* row = logits + (size_t)bt * VV;
    const int tid = threadIdx.x;

    float best = -INFINITY;
    int bidx = 0x7fffffff;
    for (int v = tid; v < VV; v += 256) {
        float x = row[v];
        if (x > best) { best = x; bidx = v; }
    }
    __shared__ float sv[256];
    __shared__ int si[256];
    sv[tid] = best;
    si[tid] = bidx;
    __syncthreads();
    for (int s = 128; s > 0; s >>= 1) {
        if (tid < s) {
            float ov = sv[tid + s];
            int oi = si[tid + s];
            if (ov > sv[tid] || (ov == sv[tid] && oi < si[tid])) {
                sv[tid] = ov;
                si[tid] = oi;
            }
        }
        __syncthreads();
    }
    if (tid == 0) preds[bt] = (float)si[0];
}

// ---------------------------------------------------------------------------
extern "C" void kernel_launch(void* const* d_in, const int* in_sizes, int n_in,
                              void* d_out, int out_size, void* d_ws, size_t ws_size,
                              hipStream_t stream) {
    const float* inputs = (const float*)d_in[0];
    const int*   targets = (const int*)d_in[1];
    const float* emb    = (const float*)d_in[2];
    const float* W_ih   = (const float*)d_in[3];
    const float* W_hh   = (const float*)d_in[4];
    const float* b_ih   = (const float*)d_in[5];
    const float* b_hh   = (const float*)d_in[6];
    const float* W_proj = (const float*)d_in[7];
    const float* b_proj = (const float*)d_in[8];

    float* out = (float*)d_out;
    float* logits = out;
    float* preds = out + (size_t)BB * TT * VV;

    // ws layout: xg | cb | Ah | Al | Bh | Bl | R
    //   R: mode<=1 -> hs,h0,h1 fp32 ; mode2 -> Wh,Wl,iah,ial,Wih_h,Wih_l,Eh,El
    float* ws = (float*)d_ws;
    float* xg = ws;                                       // [B*T,4H] f32
    float* cb = xg + (size_t)BB * TT * G4H;               // [B,H] f32
    unsigned short* Ah = (unsigned short*)(cb + (size_t)BB * HH);
    unsigned short* Al = Ah + (size_t)BB * TT * HH;
    unsigned short* Bh = Al + (size_t)BB * TT * HH;
    unsigned short* Bl = Bh + (size_t)VV * HH;
    char* R = (char*)(Bl + (size_t)VV * HH);

    // mode<=1 view of R
    float* hs = (float*)R;                                // [B*T,H]
    float* h0 = hs + (size_t)BB * TT * HH;
    float* h1 = h0 + (size_t)BB * HH;
    // mode2 view of R
    unsigned short* Wh = (unsigned short*)R;              // [4H,H] bf16
    unsigned short* Wl = Wh + (size_t)G4H * HH;
    unsigned short* iah = Wl + (size_t)G4H * HH;          // [B,H] bf16
    unsigned short* ial = iah + (size_t)BB * HH;
    unsigned short* Wih_h = ial + (size_t)BB * HH;        // [4H,D] bf16
    unsigned short* Wih_l = Wih_h + (size_t)G4H * DD;
    unsigned short* Eh = Wih_l + (size_t)G4H * DD;        // [B*T,D] bf16
    unsigned short* El = Eh + (size_t)BB * TT * DD;

    size_t base = (char*)R - (char*)d_ws;
    size_t need1 = base + ((size_t)BB * TT * HH + 2 * (size_t)BB * HH) * 4;
    size_t need2 = base + (2 * (size_t)G4H * HH + 2 * (size_t)BB * HH
                         + 2 * (size_t)G4H * DD + 2 * (size_t)BB * TT * DD) * 2;
    int mode = (ws_size >= need2) ? 2 : (ws_size >= need1) ? 1 : 0;

    if (mode >= 1) {
        split_f32<<<4096, 256, 0, stream>>>(W_proj, Bh, Bl, (long)VV * HH / 4);
    }
    if (mode == 2) {
        split_f32<<<2048, 256, 0, stream>>>(W_hh, Wh, Wl, (long)G4H * HH / 4);
        split_f32<<<32, 256, 0, stream>>>(inputs, iah, ial, (long)BB * HH / 4);
        split_f32<<<1024, 256, 0, stream>>>(W_ih, Wih_h, Wih_l, (long)G4H * DD / 4);
        emb_gather_split<<<800, 256, 0, stream>>>(targets, emb, Eh, El);
        xg_mfma<<<dim3(32, 13), 256, 0, stream>>>(Eh, El, Wih_h, Wih_l,
                                                  b_ih, b_hh, xg);
    } else {
        xg_gemm<<<dim3(64, 25), 256, 0, stream>>>(targets, emb, W_ih, b_ih, b_hh, xg);
    }

    if (mode == 2) {
        for (int t = 0; t < TT; t++) {
            const unsigned short* hh = (t == 0) ? iah : (Ah + (size_t)(t - 1) * HH);
            const unsigned short* hl = (t == 0) ? ial : (Al + (size_t)(t - 1) * HH);
            long hstride = (t == 0) ? HH : (long)TT * HH;
            lstm_mfma<<<64, 512, 0, stream>>>(Wh, Wl, xg, hh, hl, hstride,
                                              cb, Ah, Al, t);
        }
        proj_mfma<<<5200, 256, 0, stream>>>(Ah, Al, Bh, Bl, b_proj, logits);
    } else {
        for (int t = 0; t < TT; t++) {
            const float* hp = (t == 0) ? inputs : ((t & 1) ? h0 : h1);
            float* ho = (t & 1) ? h1 : h0;
            lstm_step<<<128, 256, 0, stream>>>(W_hh, xg, hp, cb, ho, hs, t);
        }
        if (mode == 1) {
            split_f32<<<1600, 256, 0, stream>>>(hs, Ah, Al, (long)BB * TT * HH / 4);
            proj_mfma<<<5200, 256, 0, stream>>>(Ah, Al, Bh, Bl, b_proj, logits);
        } else {
            proj_gemm<<<dim3(786, 25), 256, 0, stream>>>(hs, W_proj, b_proj, logits);
        }
    }

    argmax_kernel<<<1600, 256, 0, stream>>>(logits, preds);
}